// Round 3
// baseline (417.464 us; speedup 1.0000x reference)
//
#include <hip/hip_runtime.h>

// Problem constants (match reference).
#define BB 4
#define CC 64
#define HH 512
#define WW 512
#define PP 409600

// Native Clang vector types — required by __builtin_nontemporal_load/store
// (HIP_vector_type structs are rejected).
typedef float vfloat4 __attribute__((ext_vector_type(4)));
typedef int   vint4   __attribute__((ext_vector_type(4)));

// Phase 1: last-write-wins winner selection. Highest pillar index wins,
// matching sequential-assignment semantics (later writes overwrite earlier).
__global__ void pillar_winner_kernel(const vint4* __restrict__ coords,
                                     int* __restrict__ winner) {
    int p = blockIdx.x * blockDim.x + threadIdx.x;
    if (p >= PP) return;
    vint4 c = __builtin_nontemporal_load(coords + p);  // [b, z, y, x], read-once
    int b = c.x, y = c.z, x = c.w;
    if ((unsigned)y < (unsigned)HH && (unsigned)x < (unsigned)WW &&
        (unsigned)b < (unsigned)BB) {
        int flat = (b * HH + y) * WW + x;
        atomicMax(&winner[flat], p);
    }
}

// Phase 2: each thread owns 4 consecutive x positions of one (b, y) row.
// Reads 4 winner ids (vint4, coalesced, read-once -> nontemporal), gathers
// feature rows as vfloat4 (cached — reused across c4 iterations), transposes
// in registers, and streams vfloat4 stores along x for each of 64 channels
// with nontemporal hints (write-once output; keep it out of L2 so feature
// rows stay resident).
__global__ void canvas_write_kernel(const float* __restrict__ feat,
                                    const int* __restrict__ winner,
                                    float* __restrict__ out) {
    int idx = blockIdx.x * blockDim.x + threadIdx.x;   // over B*H*W/4
    int x4   = idx & (WW / 4 - 1);       // 0..127
    int rest = idx >> 7;                 // / (W/4)
    int y    = rest & (HH - 1);          // 0..511
    int b    = rest >> 9;                // 0..3

    int cell = (b * HH + y) * WW + x4 * 4;
    vint4 w = __builtin_nontemporal_load((const vint4*)(winner + cell));

    const vfloat4 zero = (vfloat4)(0.f);
    const vfloat4* fq = (const vfloat4*)feat;   // feat rows: CC/4 vfloat4 each

    // Output base for channel 0 at this (b, y, x4*4); channel stride = H*W.
    int obase = ((b * CC) * HH + y) * WW + x4 * 4;

#pragma unroll
    for (int c4 = 0; c4 < CC / 4; ++c4) {
        vfloat4 a  = (w.x >= 0) ? fq[w.x * (CC / 4) + c4] : zero;
        vfloat4 bq = (w.y >= 0) ? fq[w.y * (CC / 4) + c4] : zero;
        vfloat4 cq = (w.z >= 0) ? fq[w.z * (CC / 4) + c4] : zero;
        vfloat4 dq = (w.w >= 0) ? fq[w.w * (CC / 4) + c4] : zero;

        // Transpose: channel c4*4+j takes component j of each winner row.
        vfloat4 o0 = {a.x, bq.x, cq.x, dq.x};
        vfloat4 o1 = {a.y, bq.y, cq.y, dq.y};
        vfloat4 o2 = {a.z, bq.z, cq.z, dq.z};
        vfloat4 o3 = {a.w, bq.w, cq.w, dq.w};

        int base = obase + (c4 * 4) * (HH * WW);
        __builtin_nontemporal_store(o0, (vfloat4*)(out + base));
        __builtin_nontemporal_store(o1, (vfloat4*)(out + base + 1 * HH * WW));
        __builtin_nontemporal_store(o2, (vfloat4*)(out + base + 2 * HH * WW));
        __builtin_nontemporal_store(o3, (vfloat4*)(out + base + 3 * HH * WW));
    }
}

extern "C" void kernel_launch(void* const* d_in, const int* in_sizes, int n_in,
                              void* d_out, int out_size, void* d_ws, size_t ws_size,
                              hipStream_t stream) {
    const float* feat   = (const float*)d_in[0];   // [P, C] fp32
    const vint4* coords = (const vint4*)d_in[1];   // [P, 4] int32
    float* out          = (float*)d_out;           // [B, C, H, W] fp32
    int* winner         = (int*)d_ws;              // [B*H*W] int32 (4 MiB)

    // winner = -1 everywhere (0xFF bytes).
    (void)hipMemsetAsync(winner, 0xFF, (size_t)BB * HH * WW * sizeof(int), stream);

    // Phase 1: winner selection.
    {
        int threads = 256;
        int blocks = (PP + threads - 1) / threads;
        pillar_winner_kernel<<<blocks, threads, 0, stream>>>(coords, winner);
    }

    // Phase 2: write the full canvas.
    {
        int threads = 256;
        int total = BB * HH * WW / 4;             // 262144 threads
        int blocks = total / threads;             // 1024 blocks
        canvas_write_kernel<<<blocks, threads, 0, stream>>>(feat, winner, out);
    }
}

// Round 4
// 383.715 us; speedup vs baseline: 1.0880x; 1.0880x over previous
//
#include <hip/hip_runtime.h>

// Problem constants (match reference).
#define BB 4
#define CC 64
#define HH 512
#define WW 512
#define PP 409600

#define TILE 128   // x-cells per workgroup in phase 2
#define SMS  129   // LDS row stride (floats) for [c][x] layout; +1 pad ->
                   // scatter writes land 2-way-conflicted (free on gfx950)

// Native Clang vector types (HIP_vector_type rejected by some builtins).
typedef float vfloat4 __attribute__((ext_vector_type(4)));
typedef int   vint4   __attribute__((ext_vector_type(4)));

// Phase 1: last-write-wins winner selection. Highest pillar index wins,
// matching sequential-assignment semantics.
__global__ void pillar_winner_kernel(const vint4* __restrict__ coords,
                                     int* __restrict__ winner) {
    int p = blockIdx.x * blockDim.x + threadIdx.x;
    if (p >= PP) return;
    vint4 c = coords[p];                // [b, z, y, x]
    int b = c.x, y = c.z, x = c.w;
    if ((unsigned)y < (unsigned)HH && (unsigned)x < (unsigned)WW &&
        (unsigned)b < (unsigned)BB) {
        int flat = (b * HH + y) * WW + x;
        atomicMax(&winner[flat], p);
    }
}

// Phase 2 (LDS-staged): one 256-thread block per 128 consecutive x-cells of
// one (b, y) row. Gather winner feature rows with 16 CONTIGUOUS lanes per
// row (256 B per row segment -> every fetched HBM/L2 line fully consumed by
// a single instruction, no L1-retention dependence), transpose via LDS,
// write fully-coalesced float4 stores per channel.
__launch_bounds__(256, 4)
__global__ void canvas_write_kernel(const float* __restrict__ feat,
                                    const int* __restrict__ winner,
                                    float* __restrict__ out) {
    __shared__ float smem[CC * SMS];   // [c][x], padded stride
    __shared__ int   swin[TILE];

    int blk  = blockIdx.x;                 // over B*H*(W/TILE) = 8192
    int tx   = blk & (WW / TILE - 1);      // 0..3
    int rest = blk >> 2;
    int y    = rest & (HH - 1);            // 0..511
    int b    = rest >> 9;                  // 0..3

    int tid = threadIdx.x;
    int cellbase = (b * HH + y) * WW + tx * TILE;

    if (tid < TILE) swin[tid] = winner[cellbase + tid];
    __syncthreads();

    const vfloat4* fq  = (const vfloat4*)feat;  // rows: CC/4 float4 each
    const vfloat4 zero = (vfloat4)(0.f);

    // Gather: 128 rows x 16 float4 = 2048 loads; 8 per thread.
    // Wave pattern: lanes 0-15 read row r's float4 0..15 (256 B contiguous),
    // lanes 16-31 the next row, etc. -> 4 full-line segments per instruction.
#pragma unroll
    for (int i = 0; i < 8; ++i) {
        int flat = i * 256 + tid;
        int r = flat >> 4;                 // cell within tile
        int k = flat & 15;                 // float4 component
        int w = swin[r];
        vfloat4 v = (w >= 0) ? fq[w * (CC / 4) + k] : zero;
        int c0 = 4 * k;                    // channels c0..c0+3 of cell r
        smem[(c0 + 0) * SMS + r] = v.x;
        smem[(c0 + 1) * SMS + r] = v.y;
        smem[(c0 + 2) * SMS + r] = v.z;
        smem[(c0 + 3) * SMS + r] = v.w;
    }
    __syncthreads();

    // Store: 64 channels x 32 float4-groups = 2048 stores; 8 per thread.
    // Lanes 0-31 write channel c's full 512 B x-segment, lanes 32-63 c+1.
#pragma unroll
    for (int i = 0; i < 8; ++i) {
        int flat = i * 256 + tid;
        int c  = flat >> 5;                // 0..63
        int xg = flat & 31;                // float4 group within tile
        vfloat4 o;
        o.x = smem[c * SMS + 4 * xg + 0];
        o.y = smem[c * SMS + 4 * xg + 1];
        o.z = smem[c * SMS + 4 * xg + 2];
        o.w = smem[c * SMS + 4 * xg + 3];
        int addr = ((b * CC + c) * HH + y) * WW + tx * TILE + 4 * xg;
        *(vfloat4*)(out + addr) = o;
    }
}

extern "C" void kernel_launch(void* const* d_in, const int* in_sizes, int n_in,
                              void* d_out, int out_size, void* d_ws, size_t ws_size,
                              hipStream_t stream) {
    const float* feat   = (const float*)d_in[0];   // [P, C] fp32
    const vint4* coords = (const vint4*)d_in[1];   // [P, 4] int32
    float* out          = (float*)d_out;           // [B, C, H, W] fp32
    int* winner         = (int*)d_ws;              // [B*H*W] int32 (4 MiB)

    // winner = -1 everywhere (0xFF bytes).
    (void)hipMemsetAsync(winner, 0xFF, (size_t)BB * HH * WW * sizeof(int), stream);

    // Phase 1: winner selection.
    {
        int threads = 256;
        int blocks = (PP + threads - 1) / threads;
        pillar_winner_kernel<<<blocks, threads, 0, stream>>>(coords, winner);
    }

    // Phase 2: LDS-staged canvas write.
    {
        int threads = 256;
        int blocks = BB * HH * (WW / TILE);        // 8192
        canvas_write_kernel<<<blocks, threads, 0, stream>>>(feat, winner, out);
    }
}